// Round 5
// baseline (172.063 us; speedup 1.0000x reference)
//
#include <hip/hip_runtime.h>
#include <math.h>

constexpr int B  = 2048;
constexpr int S  = 200;
constexpr int D  = 64;
constexpr int H  = 4;
constexpr int H1 = 64;
constexpr int H2 = 32;
constexpr int F  = 256;

constexpr int PW = 72;   // bf16 LDS pitch (144 B rows, 16B-aligned, 2-way banks = free)

typedef short bf16x8 __attribute__((ext_vector_type(8)));
typedef float f32x4  __attribute__((ext_vector_type(4)));
typedef unsigned uint4v __attribute__((ext_vector_type(4)));

__device__ __forceinline__ unsigned cvtpk(float a, float b) {
    unsigned r;
    asm volatile("v_cvt_pk_bf16_f32 %0, %1, %2" : "=v"(r) : "v"(a), "v"(b));
    return r;
}
__device__ __forceinline__ float lo16f(unsigned w) { return __builtin_bit_cast(float, w << 16); }
__device__ __forceinline__ float hi16f(unsigned w) { return __builtin_bit_cast(float, w & 0xffff0000u); }

// ---------------------------------------------------------------------------
// Fused score+attend: one block per (b,h), 256 threads = 4 waves, ~26 KB LDS.
//   Weff[d][k] = W1[h,d,k] + W1[h,192+d,k] + q_d * W1[h,128+d,k]   (hi+lo bf16)
//   qt[k]      = b1[h,k] + sum_d q_d*(W1[h,64+d,k] - W1[h,192+d,k])
//   layer1 transposed (h1T = WeffT @ keysT), h1 relayed wave-privately (hi only),
//   layer2/3 -> scores in LDS -> softmax -> weighted key sum -> outh[b][h][:].
// ---------------------------------------------------------------------------
__global__ __launch_bounds__(256, 4) void score_attend_kernel(
    const float* __restrict__ query, const float* __restrict__ keys,
    const int* __restrict__ mask,
    const float* __restrict__ W1, const float* __restrict__ b1, const float* __restrict__ a1,
    const float* __restrict__ W2, const float* __restrict__ b2, const float* __restrict__ a2,
    const float* __restrict__ W3, const float* __restrict__ b3,
    float* __restrict__ outh)
{
    __shared__ union UW {
        struct { ushort WTh[H1 * PW], WTl[H1 * PW]; } w;   // build-then-dead
        ushort H1r[4][16 * PW];                            // per-wave h1 relay
    } uu;
    __shared__ ushort sW2h[H2 * PW];
    __shared__ float sQ[64], sQt[64], sQp[4][64];
    __shared__ float sB2[32], sW3v[32];
    __shared__ float sSc[208];

    // XCD-bijective swizzle: 4 h-blocks of each b adjacent in time on one XCD.
    const int wg   = blockIdx.x;
    const int rank = (wg & 7) * 1024 + (wg >> 3);
    const int b = rank >> 2;
    const int h = rank & 3;

    const int t    = threadIdx.x;
    const int lane = t & 63;
    const int wave = t >> 6;
    const int g    = lane >> 4;
    const int ln16 = lane & 15;

    const float* w1h = W1 + (size_t)h * F * H1;

    // ---- P0: stage q, W2T (hi only), b2/W3 ----
    if (t < 64) sQ[t] = query[(size_t)b * D + t];
    if (t < 32) { sB2[t] = b2[h * 32 + t]; sW3v[t] = W3[h * 32 + t]; }
    {
        const float* w2h = W2 + (size_t)h * H1 * H2;   // [k2][m]
        float4 v0 = *(const float4*)&w2h[t * 8];
        float4 v1 = *(const float4*)&w2h[t * 8 + 4];
        const int k2 = t >> 2, m0 = (t & 3) * 8;
        sW2h[(m0 + 0) * PW + k2] = (ushort)(cvtpk(v0.x, v0.x) & 0xffff);
        sW2h[(m0 + 1) * PW + k2] = (ushort)(cvtpk(v0.y, v0.y) & 0xffff);
        sW2h[(m0 + 2) * PW + k2] = (ushort)(cvtpk(v0.z, v0.z) & 0xffff);
        sW2h[(m0 + 3) * PW + k2] = (ushort)(cvtpk(v0.w, v0.w) & 0xffff);
        sW2h[(m0 + 4) * PW + k2] = (ushort)(cvtpk(v1.x, v1.x) & 0xffff);
        sW2h[(m0 + 5) * PW + k2] = (ushort)(cvtpk(v1.y, v1.y) & 0xffff);
        sW2h[(m0 + 6) * PW + k2] = (ushort)(cvtpk(v1.z, v1.z) & 0xffff);
        sW2h[(m0 + 7) * PW + k2] = (ushort)(cvtpk(v1.w, v1.w) & 0xffff);
    }
    __syncthreads();

    // ---- P1: build WeffT hi/lo (vectorized b128 writes) + qt partials ----
    {
        const int k = t & 63, dg = t >> 6;
        float qtp = 0.f;
        unsigned hiw[8], low[8];
        #pragma unroll
        for (int j2 = 0; j2 < 8; ++j2) {
            const int d0 = dg * 16 + 2 * j2, d1 = d0 + 1;
            float A0 = w1h[d0 * 64 + k], B0 = w1h[(64 + d0) * 64 + k];
            float C0 = w1h[(128 + d0) * 64 + k], D0 = w1h[(192 + d0) * 64 + k];
            float A1 = w1h[d1 * 64 + k], B1 = w1h[(64 + d1) * 64 + k];
            float C1 = w1h[(128 + d1) * 64 + k], D1 = w1h[(192 + d1) * 64 + k];
            float w0 = A0 + D0 + sQ[d0] * C0;
            float w1 = A1 + D1 + sQ[d1] * C1;
            qtp += sQ[d0] * (B0 - D0) + sQ[d1] * (B1 - D1);
            unsigned hw = cvtpk(w0, w1);
            unsigned lw = cvtpk(w0 - lo16f(hw), w1 - hi16f(hw));
            hiw[j2] = hw; low[j2] = lw;
        }
        uint4v hv0 = { hiw[0], hiw[1], hiw[2], hiw[3] };
        uint4v hv1 = { hiw[4], hiw[5], hiw[6], hiw[7] };
        uint4v lv0 = { low[0], low[1], low[2], low[3] };
        uint4v lv1 = { low[4], low[5], low[6], low[7] };
        *(uint4v*)&uu.w.WTh[k * PW + dg * 16]     = hv0;
        *(uint4v*)&uu.w.WTh[k * PW + dg * 16 + 8] = hv1;
        *(uint4v*)&uu.w.WTl[k * PW + dg * 16]     = lv0;
        *(uint4v*)&uu.w.WTl[k * PW + dg * 16 + 8] = lv1;
        sQp[dg][k] = qtp;
    }
    __syncthreads();

    // ---- hoist WeffT fragments to registers; finalize qt ----
    bf16x8 wh[4][2], wl[4][2];
    #pragma unroll
    for (int mt = 0; mt < 4; ++mt)
        #pragma unroll
        for (int kk = 0; kk < 2; ++kk) {
            int off = (mt * 16 + ln16) * PW + kk * 32 + g * 8;
            wh[mt][kk] = *(const bf16x8*)&uu.w.WTh[off];
            wl[mt][kk] = *(const bf16x8*)&uu.w.WTl[off];
        }
    if (t < 64) sQt[t] = b1[h * 64 + t] + sQp[0][t] + sQp[1][t] + sQp[2][t] + sQp[3][t];
    __syncthreads();   // after this barrier uu.w is dead -> relay may overlay

    f32x4 qtv[4];
    #pragma unroll
    for (int mt = 0; mt < 4; ++mt) qtv[mt] = *(const f32x4*)&sQt[mt * 16 + g * 4];
    f32x4 b2v[2], w3v[2];
    #pragma unroll
    for (int mt2 = 0; mt2 < 2; ++mt2) {
        b2v[mt2] = *(const f32x4*)&sB2[mt2 * 16 + g * 4];
        w3v[mt2] = *(const f32x4*)&sW3v[mt2 * 16 + g * 4];
    }
    const float a1v = a1[h], a2v = a2[h], b3v = b3[h];
    ushort* myH1 = uu.H1r[wave];

    // ---- main loop: barrier-free, 13 s-tiles over 4 waves ----
    for (int st = wave; st < 13; st += 4) {
        const int s = st * 16 + ln16;
        const int s_ld = s < 200 ? s : 199;
        const float* krow = keys + ((size_t)b * S + s_ld) * D;

        float4 kA0 = *(const float4*)&krow[g * 8];
        float4 kA1 = *(const float4*)&krow[g * 8 + 4];
        float4 kB0 = *(const float4*)&krow[32 + g * 8];
        float4 kB1 = *(const float4*)&krow[32 + g * 8 + 4];
        uint4v u0 = { cvtpk(kA0.x, kA0.y), cvtpk(kA0.z, kA0.w),
                      cvtpk(kA1.x, kA1.y), cvtpk(kA1.z, kA1.w) };
        uint4v u1 = { cvtpk(kB0.x, kB0.y), cvtpk(kB0.z, kB0.w),
                      cvtpk(kB1.x, kB1.y), cvtpk(kB1.z, kB1.w) };
        bf16x8 bk0 = __builtin_bit_cast(bf16x8, u0);
        bf16x8 bk1 = __builtin_bit_cast(bf16x8, u1);

        // layer 1 (transposed): acc[mt] holds h1T[k=16mt+4g+i][s-col=ln16]
        f32x4 acc[4] = { {0,0,0,0},{0,0,0,0},{0,0,0,0},{0,0,0,0} };
        #pragma unroll
        for (int mt = 0; mt < 4; ++mt) {
            acc[mt] = __builtin_amdgcn_mfma_f32_16x16x32_bf16(wl[mt][0], bk0, acc[mt], 0, 0, 0);
            acc[mt] = __builtin_amdgcn_mfma_f32_16x16x32_bf16(wh[mt][0], bk0, acc[mt], 0, 0, 0);
        }
        #pragma unroll
        for (int mt = 0; mt < 4; ++mt) {
            acc[mt] = __builtin_amdgcn_mfma_f32_16x16x32_bf16(wl[mt][1], bk1, acc[mt], 0, 0, 0);
            acc[mt] = __builtin_amdgcn_mfma_f32_16x16x32_bf16(wh[mt][1], bk1, acc[mt], 0, 0, 0);
        }

        // epilogue: +qt, prelu, bf16 (hi only), relay via wave-private LDS [s][k]
        #pragma unroll
        for (int mt = 0; mt < 4; ++mt) {
            float v0 = acc[mt][0] + qtv[mt][0]; v0 = v0 > 0.f ? v0 : a1v * v0;
            float v1 = acc[mt][1] + qtv[mt][1]; v1 = v1 > 0.f ? v1 : a1v * v1;
            float v2 = acc[mt][2] + qtv[mt][2]; v2 = v2 > 0.f ? v2 : a1v * v2;
            float v3 = acc[mt][3] + qtv[mt][3]; v3 = v3 > 0.f ? v3 : a1v * v3;
            unsigned hw0 = cvtpk(v0, v1), hw1 = cvtpk(v2, v3);
            *(uint2*)&myH1[ln16 * PW + mt * 16 + g * 4] = make_uint2(hw0, hw1);
        }

        // layer 2: D2[m][s] = W2T @ h1T (hi-only)
        f32x4 acc2[2] = { {0,0,0,0},{0,0,0,0} };
        #pragma unroll
        for (int w = 0; w < 2; ++w) {
            bf16x8 Bh = *(const bf16x8*)&myH1[ln16 * PW + w * 32 + g * 8];
            #pragma unroll
            for (int mt2 = 0; mt2 < 2; ++mt2) {
                bf16x8 ah = *(const bf16x8*)&sW2h[(mt2 * 16 + ln16) * PW + w * 32 + g * 8];
                acc2[mt2] = __builtin_amdgcn_mfma_f32_16x16x32_bf16(ah, Bh, acc2[mt2], 0, 0, 0);
            }
        }

        // layer 3: prelu + dot W3, reduce over lane-groups, write score to LDS
        float part = 0.f;
        #pragma unroll
        for (int mt2 = 0; mt2 < 2; ++mt2) {
            #pragma unroll
            for (int i = 0; i < 4; ++i) {
                float v = acc2[mt2][i] + b2v[mt2][i];
                v = v > 0.f ? v : a2v * v;
                part += v * w3v[mt2][i];
            }
        }
        part += __shfl_xor(part, 16);
        part += __shfl_xor(part, 32);
        if (lane < 16 && s < 200) sSc[s] = part + b3v;
    }
    __syncthreads();

    // ---- masked softmax over 200 scores (wave 0), weights in-place ----
    if (wave == 0) {
        float v[4]; int valid[4];
        float M = -INFINITY;
        #pragma unroll
        for (int c = 0; c < 4; ++c) {
            int s = lane + 64 * c;
            bool ok = s < S;
            valid[c] = ok ? mask[(size_t)b * S + s] : 0;
            v[c] = (ok && valid[c]) ? sSc[s] : -INFINITY;
            M = fmaxf(M, v[c]);
        }
        #pragma unroll
        for (int off = 32; off > 0; off >>= 1) M = fmaxf(M, __shfl_xor(M, off));
        float Z = 0.f, e[4];
        #pragma unroll
        for (int c = 0; c < 4; ++c) { e[c] = valid[c] ? __expf(v[c] - M) : 0.f; Z += e[c]; }
        #pragma unroll
        for (int off = 32; off > 0; off >>= 1) Z += __shfl_xor(Z, off);
        const float inv = Z > 0.f ? 1.f / Z : 0.f;
        #pragma unroll
        for (int c = 0; c < 4; ++c) { int s = lane + 64 * c; if (s < S) sSc[s] = e[c] * inv; }
    }
    __syncthreads();

    // ---- weighted key sum (keys re-read, L2-hot; weights broadcast from LDS) ----
    {
        const int d = lane;
        float acc = 0.f;
        #pragma unroll 5
        for (int i = 0; i < 50; ++i) {
            int s = wave * 50 + i;
            acc += sSc[s] * keys[((size_t)b * S + s) * D + d];
        }
        sQp[wave][d] = acc;
    }
    __syncthreads();
    if (t < 64)
        outh[((size_t)b * H + h) * D + t] = sQp[0][t] + sQp[1][t] + sQp[2][t] + sQp[3][t];
}

// ---------------------------------------------------------------------------
// Projection: out[b] = (mean_h outh[b,h,:]) @ Wo + bo.  4 b-rows per block.
// ---------------------------------------------------------------------------
__global__ __launch_bounds__(256) void proj_kernel(
    const float* __restrict__ outh, const float* __restrict__ Wo,
    const float* __restrict__ bo, float* __restrict__ out)
{
    __shared__ float comb[4][64];
    const int t = threadIdx.x, bb = t >> 6, j = t & 63;
    const size_t b = (size_t)blockIdx.x * 4 + bb;

    const float* oh = outh + b * H * D;
    comb[bb][j] = 0.25f * (oh[j] + oh[64 + j] + oh[128 + j] + oh[192 + j]);
    __syncthreads();

    float o = bo[j];
    #pragma unroll 8
    for (int d = 0; d < 64; ++d)
        o += comb[bb][d] * Wo[d * 64 + j];
    out[b * D + j] = o;
}

// ---------------------------------------------------------------------------
extern "C" void kernel_launch(void* const* d_in, const int* in_sizes, int n_in,
                              void* d_out, int out_size, void* d_ws, size_t ws_size,
                              hipStream_t stream) {
    const float* query = (const float*)d_in[0];
    const float* keys  = (const float*)d_in[1];
    const int*   mask  = (const int*)d_in[2];
    const float* W1 = (const float*)d_in[3];
    const float* b1 = (const float*)d_in[4];
    const float* a1 = (const float*)d_in[5];
    const float* W2 = (const float*)d_in[6];
    const float* b2 = (const float*)d_in[7];
    const float* a2 = (const float*)d_in[8];
    const float* W3 = (const float*)d_in[9];
    const float* b3 = (const float*)d_in[10];
    const float* Wo = (const float*)d_in[11];
    const float* bo = (const float*)d_in[12];

    float* out  = (float*)d_out;
    float* outh = (float*)d_ws;   // B*H*D floats = 2 MB

    score_attend_kernel<<<dim3(B * H), 256, 0, stream>>>(
        query, keys, mask, W1, b1, a1, W2, b2, a2, W3, b3, outh);
    proj_kernel<<<dim3(B / 4), 256, 0, stream>>>(outh, Wo, bo, out);
}

// Round 6
// 152.393 us; speedup vs baseline: 1.1291x; 1.1291x over previous
//
#include <hip/hip_runtime.h>
#include <math.h>

constexpr int B  = 2048;
constexpr int S  = 200;
constexpr int D  = 64;
constexpr int H  = 4;
constexpr int H1 = 64;
constexpr int H2 = 32;
constexpr int F  = 256;

constexpr int PW = 72;   // bf16 LDS pitch (144 B rows, 16B-aligned, near-uniform banks)

typedef short bf16x8 __attribute__((ext_vector_type(8)));
typedef float f32x4  __attribute__((ext_vector_type(4)));
typedef unsigned uint4v __attribute__((ext_vector_type(4)));

__device__ __forceinline__ unsigned cvtpk(float a, float b) {
    unsigned r;
    asm volatile("v_cvt_pk_bf16_f32 %0, %1, %2" : "=v"(r) : "v"(a), "v"(b));
    return r;
}
__device__ __forceinline__ float lo16f(unsigned w) { return __builtin_bit_cast(float, w << 16); }
__device__ __forceinline__ float hi16f(unsigned w) { return __builtin_bit_cast(float, w & 0xffff0000u); }

// ---------------------------------------------------------------------------
// Fused score+attend: one block per (b,h), 256 threads = 4 waves, ~26 KB LDS.
//   Weff[d][k] = W1[h,d,k] + W1[h,192+d,k] + q_d * W1[h,128+d,k]   (hi+lo bf16)
//   qt[k]      = b1[h,k] + sum_d q_d*(W1[h,64+d,k] - W1[h,192+d,k])
//   layer1 transposed (h1T = WeffT @ keysT, qt folded into acc init),
//   h1 relayed wave-privately (hi only), layer2 (b2 folded into acc init),
//   layer3 -> scores -> softmax -> weighted key sum -> outh[b][h][:].
// ---------------------------------------------------------------------------
__global__ __launch_bounds__(256, 2) void score_attend_kernel(
    const float* __restrict__ query, const float* __restrict__ keys,
    const int* __restrict__ mask,
    const float* __restrict__ W1, const float* __restrict__ b1, const float* __restrict__ a1,
    const float* __restrict__ W2, const float* __restrict__ b2, const float* __restrict__ a2,
    const float* __restrict__ W3, const float* __restrict__ b3,
    float* __restrict__ outh)
{
    __shared__ union UW {
        struct { ushort WTh[H1 * PW], WTl[H1 * PW]; } w;   // build-then-dead
        ushort H1r[4][16 * PW];                            // per-wave h1 relay
    } uu;
    __shared__ ushort sW2h[H2 * PW];
    __shared__ float sQ[64], sQt[64], sQp[4][64];
    __shared__ float sB2[32], sW3v[32];
    __shared__ float sSc[208];

    // XCD-bijective swizzle: 4 h-blocks of each b adjacent in time on one XCD.
    const int wg   = blockIdx.x;
    const int rank = (wg & 7) * 1024 + (wg >> 3);
    const int b = rank >> 2;
    const int h = rank & 3;

    const int t    = threadIdx.x;
    const int lane = t & 63;
    const int wave = t >> 6;
    const int g    = lane >> 4;
    const int ln16 = lane & 15;

    const float* w1h = W1 + (size_t)h * F * H1;

    // ---- P0: stage q, W2T (hi only, bank-rotated writes), b2/W3 ----
    if (t < 64) sQ[t] = query[(size_t)b * D + t];
    if (t < 32) { sB2[t] = b2[h * 32 + t]; sW3v[t] = W3[h * 32 + t]; }
    {
        const float* w2h = W2 + (size_t)h * H1 * H2;   // [k2][m]
        const int k2 = t >> 2, q4 = t & 3, m0 = q4 * 8;
        float v[8];
        *(float4*)&v[0] = *(const float4*)&w2h[t * 8];
        *(float4*)&v[4] = *(const float4*)&w2h[t * 8 + 4];
        #pragma unroll
        for (int j = 0; j < 8; ++j) {
            const int je = (j + k2 + q4) & 7;          // bank-spreading rotation
            sW2h[(m0 + je) * PW + k2] = (ushort)(cvtpk(v[je], v[je]) & 0xffff);
        }
    }
    __syncthreads();

    // ---- P1: build WeffT hi/lo (vectorized b128 writes) + qt partials ----
    {
        const int k = t & 63, dg = t >> 6;
        float qtp = 0.f;
        unsigned hiw[8], low[8];
        #pragma unroll
        for (int j2 = 0; j2 < 8; ++j2) {
            const int d0 = dg * 16 + 2 * j2, d1 = d0 + 1;
            float A0 = w1h[d0 * 64 + k], B0 = w1h[(64 + d0) * 64 + k];
            float C0 = w1h[(128 + d0) * 64 + k], D0 = w1h[(192 + d0) * 64 + k];
            float A1 = w1h[d1 * 64 + k], B1 = w1h[(64 + d1) * 64 + k];
            float C1 = w1h[(128 + d1) * 64 + k], D1 = w1h[(192 + d1) * 64 + k];
            float w0 = A0 + D0 + sQ[d0] * C0;
            float w1 = A1 + D1 + sQ[d1] * C1;
            qtp += sQ[d0] * (B0 - D0) + sQ[d1] * (B1 - D1);
            unsigned hw = cvtpk(w0, w1);
            unsigned lw = cvtpk(w0 - lo16f(hw), w1 - hi16f(hw));
            hiw[j2] = hw; low[j2] = lw;
        }
        uint4v hv0 = { hiw[0], hiw[1], hiw[2], hiw[3] };
        uint4v hv1 = { hiw[4], hiw[5], hiw[6], hiw[7] };
        uint4v lv0 = { low[0], low[1], low[2], low[3] };
        uint4v lv1 = { low[4], low[5], low[6], low[7] };
        *(uint4v*)&uu.w.WTh[k * PW + dg * 16]     = hv0;
        *(uint4v*)&uu.w.WTh[k * PW + dg * 16 + 8] = hv1;
        *(uint4v*)&uu.w.WTl[k * PW + dg * 16]     = lv0;
        *(uint4v*)&uu.w.WTl[k * PW + dg * 16 + 8] = lv1;
        sQp[dg][k] = qtp;
    }
    __syncthreads();

    // ---- hoist WeffT fragments to registers; finalize qt ----
    bf16x8 wh[4][2], wl[4][2];
    #pragma unroll
    for (int mt = 0; mt < 4; ++mt)
        #pragma unroll
        for (int kk = 0; kk < 2; ++kk) {
            int off = (mt * 16 + ln16) * PW + kk * 32 + g * 8;
            wh[mt][kk] = *(const bf16x8*)&uu.w.WTh[off];
            wl[mt][kk] = *(const bf16x8*)&uu.w.WTl[off];
        }
    if (t < 64) sQt[t] = b1[h * 64 + t] + sQp[0][t] + sQp[1][t] + sQp[2][t] + sQp[3][t];
    __syncthreads();   // after this barrier uu.w is dead -> relay may overlay

    f32x4 qtv[4];
    #pragma unroll
    for (int mt = 0; mt < 4; ++mt) qtv[mt] = *(const f32x4*)&sQt[mt * 16 + g * 4];
    f32x4 b2v[2], w3v[2];
    #pragma unroll
    for (int mt2 = 0; mt2 < 2; ++mt2) {
        b2v[mt2] = *(const f32x4*)&sB2[mt2 * 16 + g * 4];
        w3v[mt2] = *(const f32x4*)&sW3v[mt2 * 16 + g * 4];
    }
    const float a1v = a1[h], a2v = a2[h], b3v = b3[h];
    ushort* myH1 = uu.H1r[wave];

    // ---- main loop: barrier-free, 13 s-tiles over 4 waves ----
    for (int st = wave; st < 13; st += 4) {
        const int s = st * 16 + ln16;
        const int s_ld = s < 200 ? s : 199;
        const float* krow = keys + ((size_t)b * S + s_ld) * D;

        float4 kA0 = *(const float4*)&krow[g * 8];
        float4 kA1 = *(const float4*)&krow[g * 8 + 4];
        float4 kB0 = *(const float4*)&krow[32 + g * 8];
        float4 kB1 = *(const float4*)&krow[32 + g * 8 + 4];
        uint4v u0 = { cvtpk(kA0.x, kA0.y), cvtpk(kA0.z, kA0.w),
                      cvtpk(kA1.x, kA1.y), cvtpk(kA1.z, kA1.w) };
        uint4v u1 = { cvtpk(kB0.x, kB0.y), cvtpk(kB0.z, kB0.w),
                      cvtpk(kB1.x, kB1.y), cvtpk(kB1.z, kB1.w) };
        bf16x8 bk0 = __builtin_bit_cast(bf16x8, u0);
        bf16x8 bk1 = __builtin_bit_cast(bf16x8, u1);

        // layer 1 (transposed): acc[mt] = h1T[k=16mt+4g+i][s=ln16], qt pre-loaded as C
        f32x4 acc[4] = { qtv[0], qtv[1], qtv[2], qtv[3] };
        #pragma unroll
        for (int mt = 0; mt < 4; ++mt) {
            acc[mt] = __builtin_amdgcn_mfma_f32_16x16x32_bf16(wl[mt][0], bk0, acc[mt], 0, 0, 0);
            acc[mt] = __builtin_amdgcn_mfma_f32_16x16x32_bf16(wh[mt][0], bk0, acc[mt], 0, 0, 0);
        }
        #pragma unroll
        for (int mt = 0; mt < 4; ++mt) {
            acc[mt] = __builtin_amdgcn_mfma_f32_16x16x32_bf16(wl[mt][1], bk1, acc[mt], 0, 0, 0);
            acc[mt] = __builtin_amdgcn_mfma_f32_16x16x32_bf16(wh[mt][1], bk1, acc[mt], 0, 0, 0);
        }

        // epilogue: prelu, bf16 (hi only), relay via wave-private LDS [s][k]
        #pragma unroll
        for (int mt = 0; mt < 4; ++mt) {
            float v0 = acc[mt][0]; v0 = v0 > 0.f ? v0 : a1v * v0;
            float v1 = acc[mt][1]; v1 = v1 > 0.f ? v1 : a1v * v1;
            float v2 = acc[mt][2]; v2 = v2 > 0.f ? v2 : a1v * v2;
            float v3 = acc[mt][3]; v3 = v3 > 0.f ? v3 : a1v * v3;
            unsigned hw0 = cvtpk(v0, v1), hw1 = cvtpk(v2, v3);
            *(uint2*)&myH1[ln16 * PW + mt * 16 + g * 4] = make_uint2(hw0, hw1);
        }

        // layer 2: D2[m][s] = W2T @ h1T (hi-only), b2 pre-loaded as C
        f32x4 acc2[2] = { b2v[0], b2v[1] };
        #pragma unroll
        for (int w = 0; w < 2; ++w) {
            bf16x8 Bh = *(const bf16x8*)&myH1[ln16 * PW + w * 32 + g * 8];
            #pragma unroll
            for (int mt2 = 0; mt2 < 2; ++mt2) {
                bf16x8 ah = *(const bf16x8*)&sW2h[(mt2 * 16 + ln16) * PW + w * 32 + g * 8];
                acc2[mt2] = __builtin_amdgcn_mfma_f32_16x16x32_bf16(ah, Bh, acc2[mt2], 0, 0, 0);
            }
        }

        // layer 3: prelu + dot W3, reduce over lane-groups, write score to LDS
        float part = 0.f;
        #pragma unroll
        for (int mt2 = 0; mt2 < 2; ++mt2) {
            #pragma unroll
            for (int i = 0; i < 4; ++i) {
                float v = acc2[mt2][i];
                v = v > 0.f ? v : a2v * v;
                part += v * w3v[mt2][i];
            }
        }
        part += __shfl_xor(part, 16);
        part += __shfl_xor(part, 32);
        if (lane < 16 && s < 200) sSc[s] = part + b3v;
    }
    __syncthreads();

    // ---- masked softmax over 200 scores (wave 0), weights in-place ----
    if (wave == 0) {
        float v[4]; int valid[4];
        float M = -INFINITY;
        #pragma unroll
        for (int c = 0; c < 4; ++c) {
            int s = lane + 64 * c;
            bool ok = s < S;
            valid[c] = ok ? mask[(size_t)b * S + s] : 0;
            v[c] = (ok && valid[c]) ? sSc[s] : -INFINITY;
            M = fmaxf(M, v[c]);
        }
        #pragma unroll
        for (int off = 32; off > 0; off >>= 1) M = fmaxf(M, __shfl_xor(M, off));
        float Z = 0.f, e[4];
        #pragma unroll
        for (int c = 0; c < 4; ++c) { e[c] = valid[c] ? __expf(v[c] - M) : 0.f; Z += e[c]; }
        #pragma unroll
        for (int off = 32; off > 0; off >>= 1) Z += __shfl_xor(Z, off);
        const float inv = Z > 0.f ? 1.f / Z : 0.f;
        #pragma unroll
        for (int c = 0; c < 4; ++c) { int s = lane + 64 * c; if (s < S) sSc[s] = e[c] * inv; }
    }
    __syncthreads();

    // ---- weighted key sum (keys re-read, L2-hot; weights broadcast from LDS) ----
    {
        const int d = lane;
        float acc = 0.f;
        #pragma unroll 5
        for (int i = 0; i < 50; ++i) {
            int s = wave * 50 + i;
            acc += sSc[s] * keys[((size_t)b * S + s) * D + d];
        }
        sQp[wave][d] = acc;
    }
    __syncthreads();
    if (t < 64)
        outh[((size_t)b * H + h) * D + t] = sQp[0][t] + sQp[1][t] + sQp[2][t] + sQp[3][t];
}

// ---------------------------------------------------------------------------
// Projection: out[b] = (mean_h outh[b,h,:]) @ Wo + bo.  4 b-rows per block.
// ---------------------------------------------------------------------------
__global__ __launch_bounds__(256) void proj_kernel(
    const float* __restrict__ outh, const float* __restrict__ Wo,
    const float* __restrict__ bo, float* __restrict__ out)
{
    __shared__ float comb[4][64];
    const int t = threadIdx.x, bb = t >> 6, j = t & 63;
    const size_t b = (size_t)blockIdx.x * 4 + bb;

    const float* oh = outh + b * H * D;
    comb[bb][j] = 0.25f * (oh[j] + oh[64 + j] + oh[128 + j] + oh[192 + j]);
    __syncthreads();

    float o = bo[j];
    #pragma unroll 8
    for (int d = 0; d < 64; ++d)
        o += comb[bb][d] * Wo[d * 64 + j];
    out[b * D + j] = o;
}

// ---------------------------------------------------------------------------
extern "C" void kernel_launch(void* const* d_in, const int* in_sizes, int n_in,
                              void* d_out, int out_size, void* d_ws, size_t ws_size,
                              hipStream_t stream) {
    const float* query = (const float*)d_in[0];
    const float* keys  = (const float*)d_in[1];
    const int*   mask  = (const int*)d_in[2];
    const float* W1 = (const float*)d_in[3];
    const float* b1 = (const float*)d_in[4];
    const float* a1 = (const float*)d_in[5];
    const float* W2 = (const float*)d_in[6];
    const float* b2 = (const float*)d_in[7];
    const float* a2 = (const float*)d_in[8];
    const float* W3 = (const float*)d_in[9];
    const float* b3 = (const float*)d_in[10];
    const float* Wo = (const float*)d_in[11];
    const float* bo = (const float*)d_in[12];

    float* out  = (float*)d_out;
    float* outh = (float*)d_ws;   // B*H*D floats = 2 MB

    score_attend_kernel<<<dim3(B * H), 256, 0, stream>>>(
        query, keys, mask, W1, b1, a1, W2, b2, a2, W3, b3, outh);
    proj_kernel<<<dim3(B / 4), 256, 0, stream>>>(outh, Wo, bo, out);
}

// Round 7
// 130.800 us; speedup vs baseline: 1.3155x; 1.1651x over previous
//
#include <hip/hip_runtime.h>
#include <math.h>

constexpr int B  = 2048;
constexpr int S  = 200;
constexpr int D  = 64;
constexpr int H  = 4;
constexpr int H1 = 64;
constexpr int H2 = 32;
constexpr int F  = 256;

constexpr int PW = 72;   // bf16 LDS pitch (144 B rows; main-loop patterns bank-uniform)

typedef short bf16x8 __attribute__((ext_vector_type(8)));
typedef float f32x4  __attribute__((ext_vector_type(4)));
typedef unsigned uint4v __attribute__((ext_vector_type(4)));

__device__ __forceinline__ unsigned cvtpk(float a, float b) {
    unsigned r;
    asm volatile("v_cvt_pk_bf16_f32 %0, %1, %2" : "=v"(r) : "v"(a), "v"(b));
    return r;
}
__device__ __forceinline__ float lo16f(unsigned w) { return __builtin_bit_cast(float, w << 16); }
__device__ __forceinline__ float hi16f(unsigned w) { return __builtin_bit_cast(float, w & 0xffff0000u); }

// ---------------------------------------------------------------------------
// Fused score+attend: one block per (b,h), 256 threads = 4 waves, ~26 KB LDS.
//   Weff[d][k] = W1[h,d,k] + W1[h,192+d,k] + q_d * W1[h,128+d,k]   (hi+lo bf16)
//   qt[k]      = b1[h,k] + sum_d q_d*(W1[h,64+d,k] - W1[h,192+d,k])
//   layer1 transposed (h1T = WeffT @ keysT, qt folded into acc init),
//   h1 relayed wave-privately (hi only), layer2 (b2 folded into acc init),
//   layer3 -> scores -> softmax -> weighted key sum -> outh[b][h][:].
// ---------------------------------------------------------------------------
__global__ __launch_bounds__(256, 2) void score_attend_kernel(
    const float* __restrict__ query, const float* __restrict__ keys,
    const int* __restrict__ mask,
    const float* __restrict__ W1, const float* __restrict__ b1, const float* __restrict__ a1,
    const float* __restrict__ W2, const float* __restrict__ b2, const float* __restrict__ a2,
    const float* __restrict__ W3, const float* __restrict__ b3,
    float* __restrict__ outh)
{
    __shared__ union UW {
        struct { ushort WTh[H1 * PW], WTl[H1 * PW]; } w;   // build-then-dead
        ushort H1r[4][16 * PW];                            // per-wave h1 relay
    } uu;
    __shared__ ushort sW2h[H2 * PW];
    __shared__ float sQ[64], sQt[64], sQp[4][64];
    __shared__ float sB2[32], sW3v[32];
    __shared__ float sSc[208];

    // XCD-bijective swizzle: 4 h-blocks of each b adjacent in time on one XCD.
    const int wg   = blockIdx.x;
    const int rank = (wg & 7) * 1024 + (wg >> 3);
    const int b = rank >> 2;
    const int h = rank & 3;

    const int t    = threadIdx.x;
    const int lane = t & 63;
    const int wave = t >> 6;
    const int g    = lane >> 4;
    const int ln16 = lane & 15;

    const float* w1h = W1 + (size_t)h * F * H1;

    // ---- prefetch mask early (consumed after the main loop by wave 3) ----
    int mval[4] = {0, 0, 0, 0};
    if (wave == 3) {
        #pragma unroll
        for (int c = 0; c < 4; ++c) {
            int s = lane + 64 * c;
            mval[c] = (s < S) ? mask[(size_t)b * S + s] : 0;
        }
    }

    // ---- P0: stage q, W2T (hi only, constant-indexed stores), b2/W3 ----
    if (t < 64) sQ[t] = query[(size_t)b * D + t];
    if (t < 32) { sB2[t] = b2[h * 32 + t]; sW3v[t] = W3[h * 32 + t]; }
    {
        const float* w2h = W2 + (size_t)h * H1 * H2;   // [k2][m]
        float4 va = *(const float4*)&w2h[t * 8];
        float4 vb = *(const float4*)&w2h[t * 8 + 4];
        const int k2 = t >> 2, m0 = (t & 3) * 8;
        sW2h[(m0 + 0) * PW + k2] = (ushort)(cvtpk(va.x, va.x) & 0xffff);
        sW2h[(m0 + 1) * PW + k2] = (ushort)(cvtpk(va.y, va.y) & 0xffff);
        sW2h[(m0 + 2) * PW + k2] = (ushort)(cvtpk(va.z, va.z) & 0xffff);
        sW2h[(m0 + 3) * PW + k2] = (ushort)(cvtpk(va.w, va.w) & 0xffff);
        sW2h[(m0 + 4) * PW + k2] = (ushort)(cvtpk(vb.x, vb.x) & 0xffff);
        sW2h[(m0 + 5) * PW + k2] = (ushort)(cvtpk(vb.y, vb.y) & 0xffff);
        sW2h[(m0 + 6) * PW + k2] = (ushort)(cvtpk(vb.z, vb.z) & 0xffff);
        sW2h[(m0 + 7) * PW + k2] = (ushort)(cvtpk(vb.w, vb.w) & 0xffff);
    }
    __syncthreads();

    // ---- P1: build WeffT hi/lo (vectorized b128 writes) + qt partials ----
    {
        const int k = t & 63, dg = t >> 6;
        float qtp = 0.f;
        unsigned hiw[8], low[8];
        #pragma unroll
        for (int j2 = 0; j2 < 8; ++j2) {
            const int d0 = dg * 16 + 2 * j2, d1 = d0 + 1;
            float A0 = w1h[d0 * 64 + k], B0 = w1h[(64 + d0) * 64 + k];
            float C0 = w1h[(128 + d0) * 64 + k], D0 = w1h[(192 + d0) * 64 + k];
            float A1 = w1h[d1 * 64 + k], B1 = w1h[(64 + d1) * 64 + k];
            float C1 = w1h[(128 + d1) * 64 + k], D1 = w1h[(192 + d1) * 64 + k];
            float w0 = A0 + D0 + sQ[d0] * C0;
            float w1 = A1 + D1 + sQ[d1] * C1;
            qtp += sQ[d0] * (B0 - D0) + sQ[d1] * (B1 - D1);
            unsigned hw = cvtpk(w0, w1);
            unsigned lw = cvtpk(w0 - lo16f(hw), w1 - hi16f(hw));
            hiw[j2] = hw; low[j2] = lw;
        }
        uint4v hv0 = { hiw[0], hiw[1], hiw[2], hiw[3] };
        uint4v hv1 = { hiw[4], hiw[5], hiw[6], hiw[7] };
        uint4v lv0 = { low[0], low[1], low[2], low[3] };
        uint4v lv1 = { low[4], low[5], low[6], low[7] };
        *(uint4v*)&uu.w.WTh[k * PW + dg * 16]     = hv0;
        *(uint4v*)&uu.w.WTh[k * PW + dg * 16 + 8] = hv1;
        *(uint4v*)&uu.w.WTl[k * PW + dg * 16]     = lv0;
        *(uint4v*)&uu.w.WTl[k * PW + dg * 16 + 8] = lv1;
        sQp[dg][k] = qtp;
    }
    __syncthreads();

    // ---- hoist WeffT fragments to registers; finalize qt ----
    bf16x8 wh[4][2], wl[4][2];
    #pragma unroll
    for (int mt = 0; mt < 4; ++mt)
        #pragma unroll
        for (int kk = 0; kk < 2; ++kk) {
            int off = (mt * 16 + ln16) * PW + kk * 32 + g * 8;
            wh[mt][kk] = *(const bf16x8*)&uu.w.WTh[off];
            wl[mt][kk] = *(const bf16x8*)&uu.w.WTl[off];
        }
    if (t < 64) sQt[t] = b1[h * 64 + t] + sQp[0][t] + sQp[1][t] + sQp[2][t] + sQp[3][t];
    __syncthreads();   // after this barrier uu.w is dead -> relay may overlay

    f32x4 qtv[4];
    #pragma unroll
    for (int mt = 0; mt < 4; ++mt) qtv[mt] = *(const f32x4*)&sQt[mt * 16 + g * 4];
    f32x4 b2v[2], w3v[2];
    #pragma unroll
    for (int mt2 = 0; mt2 < 2; ++mt2) {
        b2v[mt2] = *(const f32x4*)&sB2[mt2 * 16 + g * 4];
        w3v[mt2] = *(const f32x4*)&sW3v[mt2 * 16 + g * 4];
    }
    const float a1v = a1[h], a2v = a2[h], b3v = b3[h];
    ushort* myH1 = uu.H1r[wave];

    // ---- main loop: barrier-free, 13 s-tiles over 4 waves ----
    for (int st = wave; st < 13; st += 4) {
        const int s = st * 16 + ln16;
        const int s_ld = s < 200 ? s : 199;
        const float* krow = keys + ((size_t)b * S + s_ld) * D;

        float4 kA0 = *(const float4*)&krow[g * 8];
        float4 kA1 = *(const float4*)&krow[g * 8 + 4];
        float4 kB0 = *(const float4*)&krow[32 + g * 8];
        float4 kB1 = *(const float4*)&krow[32 + g * 8 + 4];
        uint4v u0 = { cvtpk(kA0.x, kA0.y), cvtpk(kA0.z, kA0.w),
                      cvtpk(kA1.x, kA1.y), cvtpk(kA1.z, kA1.w) };
        uint4v u1 = { cvtpk(kB0.x, kB0.y), cvtpk(kB0.z, kB0.w),
                      cvtpk(kB1.x, kB1.y), cvtpk(kB1.z, kB1.w) };
        bf16x8 bk0 = __builtin_bit_cast(bf16x8, u0);
        bf16x8 bk1 = __builtin_bit_cast(bf16x8, u1);

        // layer 1 (transposed): acc[mt] = h1T[k=16mt+4g+i][s=ln16], qt pre-loaded as C
        f32x4 acc[4] = { qtv[0], qtv[1], qtv[2], qtv[3] };
        #pragma unroll
        for (int mt = 0; mt < 4; ++mt) {
            acc[mt] = __builtin_amdgcn_mfma_f32_16x16x32_bf16(wl[mt][0], bk0, acc[mt], 0, 0, 0);
            acc[mt] = __builtin_amdgcn_mfma_f32_16x16x32_bf16(wh[mt][0], bk0, acc[mt], 0, 0, 0);
        }
        #pragma unroll
        for (int mt = 0; mt < 4; ++mt) {
            acc[mt] = __builtin_amdgcn_mfma_f32_16x16x32_bf16(wl[mt][1], bk1, acc[mt], 0, 0, 0);
            acc[mt] = __builtin_amdgcn_mfma_f32_16x16x32_bf16(wh[mt][1], bk1, acc[mt], 0, 0, 0);
        }

        // epilogue: prelu, bf16 (hi only), relay via wave-private LDS [s][k]
        #pragma unroll
        for (int mt = 0; mt < 4; ++mt) {
            float v0 = acc[mt][0]; v0 = v0 > 0.f ? v0 : a1v * v0;
            float v1 = acc[mt][1]; v1 = v1 > 0.f ? v1 : a1v * v1;
            float v2 = acc[mt][2]; v2 = v2 > 0.f ? v2 : a1v * v2;
            float v3 = acc[mt][3]; v3 = v3 > 0.f ? v3 : a1v * v3;
            unsigned hw0 = cvtpk(v0, v1), hw1 = cvtpk(v2, v3);
            *(uint2*)&myH1[ln16 * PW + mt * 16 + g * 4] = make_uint2(hw0, hw1);
        }

        // layer 2: D2[m][s] = W2T @ h1T (hi-only), b2 pre-loaded as C
        f32x4 acc2[2] = { b2v[0], b2v[1] };
        #pragma unroll
        for (int w = 0; w < 2; ++w) {
            bf16x8 Bh = *(const bf16x8*)&myH1[ln16 * PW + w * 32 + g * 8];
            #pragma unroll
            for (int mt2 = 0; mt2 < 2; ++mt2) {
                bf16x8 ah = *(const bf16x8*)&sW2h[(mt2 * 16 + ln16) * PW + w * 32 + g * 8];
                acc2[mt2] = __builtin_amdgcn_mfma_f32_16x16x32_bf16(ah, Bh, acc2[mt2], 0, 0, 0);
            }
        }

        // layer 3: prelu + dot W3, reduce over lane-groups, write score to LDS
        float part = 0.f;
        #pragma unroll
        for (int mt2 = 0; mt2 < 2; ++mt2) {
            #pragma unroll
            for (int i = 0; i < 4; ++i) {
                float v = acc2[mt2][i];
                v = v > 0.f ? v : a2v * v;
                part += v * w3v[mt2][i];
            }
        }
        part += __shfl_xor(part, 16);
        part += __shfl_xor(part, 32);
        if (lane < 16 && s < 200) sSc[s] = part + b3v;
    }
    __syncthreads();

    // ---- masked softmax over 200 scores (wave 3: it ran only 3 s-tiles and
    //      already holds the prefetched mask), weights written in-place ----
    if (wave == 3) {
        float v[4];
        float M = -INFINITY;
        #pragma unroll
        for (int c = 0; c < 4; ++c) {
            int s = lane + 64 * c;
            v[c] = (s < S && mval[c]) ? sSc[s] : -INFINITY;
            M = fmaxf(M, v[c]);
        }
        #pragma unroll
        for (int off = 32; off > 0; off >>= 1) M = fmaxf(M, __shfl_xor(M, off));
        float Z = 0.f, e[4];
        #pragma unroll
        for (int c = 0; c < 4; ++c) { e[c] = mval[c] ? __expf(v[c] - M) : 0.f; Z += e[c]; }
        #pragma unroll
        for (int off = 32; off > 0; off >>= 1) Z += __shfl_xor(Z, off);
        const float inv = Z > 0.f ? 1.f / Z : 0.f;
        #pragma unroll
        for (int c = 0; c < 4; ++c) { int s = lane + 64 * c; if (s < S) sSc[s] = e[c] * inv; }
    }
    __syncthreads();

    // ---- weighted key sum (keys re-read, L2-hot; weights broadcast from LDS) ----
    {
        const int d = lane;
        float acc = 0.f;
        #pragma unroll 5
        for (int i = 0; i < 50; ++i) {
            int s = wave * 50 + i;
            acc += sSc[s] * keys[((size_t)b * S + s) * D + d];
        }
        sQp[wave][d] = acc;
    }
    __syncthreads();
    if (t < 64)
        outh[((size_t)b * H + h) * D + t] = sQp[0][t] + sQp[1][t] + sQp[2][t] + sQp[3][t];
}

// ---------------------------------------------------------------------------
// Projection: out[b] = (mean_h outh[b,h,:]) @ Wo + bo.  4 b-rows per block.
// ---------------------------------------------------------------------------
__global__ __launch_bounds__(256) void proj_kernel(
    const float* __restrict__ outh, const float* __restrict__ Wo,
    const float* __restrict__ bo, float* __restrict__ out)
{
    __shared__ float comb[4][64];
    const int t = threadIdx.x, bb = t >> 6, j = t & 63;
    const size_t b = (size_t)blockIdx.x * 4 + bb;

    const float* oh = outh + b * H * D;
    comb[bb][j] = 0.25f * (oh[j] + oh[64 + j] + oh[128 + j] + oh[192 + j]);
    __syncthreads();

    float o = bo[j];
    #pragma unroll 8
    for (int d = 0; d < 64; ++d)
        o += comb[bb][d] * Wo[d * 64 + j];
    out[b * D + j] = o;
}

// ---------------------------------------------------------------------------
extern "C" void kernel_launch(void* const* d_in, const int* in_sizes, int n_in,
                              void* d_out, int out_size, void* d_ws, size_t ws_size,
                              hipStream_t stream) {
    const float* query = (const float*)d_in[0];
    const float* keys  = (const float*)d_in[1];
    const int*   mask  = (const int*)d_in[2];
    const float* W1 = (const float*)d_in[3];
    const float* b1 = (const float*)d_in[4];
    const float* a1 = (const float*)d_in[5];
    const float* W2 = (const float*)d_in[6];
    const float* b2 = (const float*)d_in[7];
    const float* a2 = (const float*)d_in[8];
    const float* W3 = (const float*)d_in[9];
    const float* b3 = (const float*)d_in[10];
    const float* Wo = (const float*)d_in[11];
    const float* bo = (const float*)d_in[12];

    float* out  = (float*)d_out;
    float* outh = (float*)d_ws;   // B*H*D floats = 2 MB

    score_attend_kernel<<<dim3(B * H), 256, 0, stream>>>(
        query, keys, mask, W1, b1, a1, W2, b2, a2, W3, b3, outh);
    proj_kernel<<<dim3(B / 4), 256, 0, stream>>>(outh, Wo, bo, out);
}

// Round 8
// 105.155 us; speedup vs baseline: 1.6363x; 1.2439x over previous
//
#include <hip/hip_runtime.h>
#include <math.h>

constexpr int B  = 2048;
constexpr int S  = 200;
constexpr int D  = 64;
constexpr int H  = 4;
constexpr int H1 = 64;
constexpr int H2 = 32;
constexpr int F  = 256;

constexpr int PW = 72;   // bf16 LDS pitch (144 B rows; frag patterns ~2-way banks = free)

typedef short bf16x8 __attribute__((ext_vector_type(8)));
typedef float f32x4  __attribute__((ext_vector_type(4)));
typedef unsigned uint4v __attribute__((ext_vector_type(4)));

__device__ __forceinline__ unsigned cvtpk(float a, float b) {
    unsigned r;
    asm volatile("v_cvt_pk_bf16_f32 %0, %1, %2" : "=v"(r) : "v"(a), "v"(b));
    return r;
}

struct K4 { float4 a, b, c, d; };

// ---------------------------------------------------------------------------
// Fused score+attend: one block per (b,h), 256 threads = 4 waves, ~16 KB LDS.
//   Weff[d][k] = W1[h,d,k] + W1[h,192+d,k] + q_d * W1[h,128+d,k]   (hi bf16)
//   qt[k]      = b1[h,k] + sum_d q_d*(W1[h,64+d,k] - W1[h,192+d,k])
//   layer1 transposed (h1T = WeffT @ keysT, qt folded into acc init),
//   keys software-pipelined (next tile prefetched during current compute),
//   h1 relayed wave-privately, layer2 (b2 folded), layer3 -> scores ->
//   softmax -> weighted key sum -> outh[b][h][:].
// ---------------------------------------------------------------------------
__global__ __launch_bounds__(256, 2) void score_attend_kernel(
    const float* __restrict__ query, const float* __restrict__ keys,
    const int* __restrict__ mask,
    const float* __restrict__ W1, const float* __restrict__ b1, const float* __restrict__ a1,
    const float* __restrict__ W2, const float* __restrict__ b2, const float* __restrict__ a2,
    const float* __restrict__ W3, const float* __restrict__ b3,
    float* __restrict__ outh)
{
    __shared__ union UW {
        ushort WTh[H1 * PW];        // WeffT [k][d] hi  (build-then-dead)
        ushort H1r[4][16 * PW];     // per-wave h1 relay
    } uu;
    __shared__ ushort sW2h[H2 * PW];
    __shared__ float sQ[64], sQt[64], sQp[4][64];
    __shared__ float sB2[32], sW3v[32];
    __shared__ float sSc[208];

    // XCD-bijective swizzle: 4 h-blocks of each b adjacent in time on one XCD.
    const int wg   = blockIdx.x;
    const int rank = (wg & 7) * 1024 + (wg >> 3);
    const int b = rank >> 2;
    const int h = rank & 3;

    const int t    = threadIdx.x;
    const int lane = t & 63;
    const int wave = t >> 6;
    const int g    = lane >> 4;
    const int ln16 = lane & 15;

    const float* w1h = W1 + (size_t)h * F * H1;

    auto loadKeys = [&](int st) -> K4 {
        int s = st * 16 + ln16;
        if (s > 199) s = 199;
        const float* krow = keys + ((size_t)b * S + s) * D;
        K4 r;
        r.a = *(const float4*)&krow[g * 8];
        r.b = *(const float4*)&krow[g * 8 + 4];
        r.c = *(const float4*)&krow[32 + g * 8];
        r.d = *(const float4*)&krow[32 + g * 8 + 4];
        return r;
    };

    // ---- issue first tile's keys immediately (hidden under entire prologue) ----
    K4 cur = loadKeys(wave);

    // ---- prefetch mask early (consumed after the main loop by wave 3) ----
    int mval[4] = {0, 0, 0, 0};
    if (wave == 3) {
        #pragma unroll
        for (int c = 0; c < 4; ++c) {
            int s = lane + 64 * c;
            mval[c] = (s < S) ? mask[(size_t)b * S + s] : 0;
        }
    }

    // ---- P0: stage q, W2T hi (vectorized b128 write), b2/W3 ----
    if (t < 64) sQ[t] = query[(size_t)b * D + t];
    if (t < 32) { sB2[t] = b2[h * 32 + t]; sW3v[t] = W3[h * 32 + t]; }
    {
        const float* w2h = W2 + (size_t)h * H1 * H2;   // [k2][m]
        const int m = t & 31, kg = t >> 5;             // thread owns 8 k2 for one m
        unsigned pk0 = cvtpk(w2h[(kg * 8 + 0) * 32 + m], w2h[(kg * 8 + 1) * 32 + m]);
        unsigned pk1 = cvtpk(w2h[(kg * 8 + 2) * 32 + m], w2h[(kg * 8 + 3) * 32 + m]);
        unsigned pk2 = cvtpk(w2h[(kg * 8 + 4) * 32 + m], w2h[(kg * 8 + 5) * 32 + m]);
        unsigned pk3 = cvtpk(w2h[(kg * 8 + 6) * 32 + m], w2h[(kg * 8 + 7) * 32 + m]);
        uint4v v = { pk0, pk1, pk2, pk3 };
        *(uint4v*)&sW2h[m * PW + kg * 8] = v;
    }
    __syncthreads();

    // ---- P1: build WeffT hi (b128 writes) + qt partials ----
    {
        const int k = t & 63, dg = t >> 6;
        float qtp = 0.f;
        unsigned hw[8];
        #pragma unroll
        for (int j2 = 0; j2 < 8; ++j2) {
            const int d0 = dg * 16 + 2 * j2, d1 = d0 + 1;
            float A0 = w1h[d0 * 64 + k], B0 = w1h[(64 + d0) * 64 + k];
            float C0 = w1h[(128 + d0) * 64 + k], D0 = w1h[(192 + d0) * 64 + k];
            float A1 = w1h[d1 * 64 + k], B1 = w1h[(64 + d1) * 64 + k];
            float C1 = w1h[(128 + d1) * 64 + k], D1 = w1h[(192 + d1) * 64 + k];
            float w0 = A0 + D0 + sQ[d0] * C0;
            float w1 = A1 + D1 + sQ[d1] * C1;
            qtp += sQ[d0] * (B0 - D0) + sQ[d1] * (B1 - D1);
            hw[j2] = cvtpk(w0, w1);
        }
        uint4v hv0 = { hw[0], hw[1], hw[2], hw[3] };
        uint4v hv1 = { hw[4], hw[5], hw[6], hw[7] };
        *(uint4v*)&uu.WTh[k * PW + dg * 16]     = hv0;
        *(uint4v*)&uu.WTh[k * PW + dg * 16 + 8] = hv1;
        sQp[dg][k] = qtp;
    }
    __syncthreads();

    // ---- hoist WeffT fragments to registers; finalize qt ----
    bf16x8 wh[4][2];
    #pragma unroll
    for (int mt = 0; mt < 4; ++mt)
        #pragma unroll
        for (int kk = 0; kk < 2; ++kk)
            wh[mt][kk] = *(const bf16x8*)&uu.WTh[(mt * 16 + ln16) * PW + kk * 32 + g * 8];
    if (t < 64) sQt[t] = b1[h * 64 + t] + sQp[0][t] + sQp[1][t] + sQp[2][t] + sQp[3][t];
    __syncthreads();   // after this barrier uu.WTh is dead -> relay overlays

    f32x4 qtv[4];
    #pragma unroll
    for (int mt = 0; mt < 4; ++mt) qtv[mt] = *(const f32x4*)&sQt[mt * 16 + g * 4];
    f32x4 b2v[2], w3v[2];
    #pragma unroll
    for (int mt2 = 0; mt2 < 2; ++mt2) {
        b2v[mt2] = *(const f32x4*)&sB2[mt2 * 16 + g * 4];
        w3v[mt2] = *(const f32x4*)&sW3v[mt2 * 16 + g * 4];
    }
    const float a1v = a1[h], a2v = a2[h], b3v = b3[h];
    ushort* myH1 = uu.H1r[wave];

    auto computeTile = [&](const K4& kf, int st) {
        uint4v u0 = { cvtpk(kf.a.x, kf.a.y), cvtpk(kf.a.z, kf.a.w),
                      cvtpk(kf.b.x, kf.b.y), cvtpk(kf.b.z, kf.b.w) };
        uint4v u1 = { cvtpk(kf.c.x, kf.c.y), cvtpk(kf.c.z, kf.c.w),
                      cvtpk(kf.d.x, kf.d.y), cvtpk(kf.d.z, kf.d.w) };
        bf16x8 bk0 = __builtin_bit_cast(bf16x8, u0);
        bf16x8 bk1 = __builtin_bit_cast(bf16x8, u1);

        // layer 1 (transposed): acc[mt] = h1T[k=16mt+4g+i][s=ln16], qt as C-init
        f32x4 acc[4] = { qtv[0], qtv[1], qtv[2], qtv[3] };
        #pragma unroll
        for (int mt = 0; mt < 4; ++mt)
            acc[mt] = __builtin_amdgcn_mfma_f32_16x16x32_bf16(wh[mt][0], bk0, acc[mt], 0, 0, 0);
        #pragma unroll
        for (int mt = 0; mt < 4; ++mt)
            acc[mt] = __builtin_amdgcn_mfma_f32_16x16x32_bf16(wh[mt][1], bk1, acc[mt], 0, 0, 0);

        // epilogue: prelu, bf16 hi, relay via wave-private LDS [s][k]
        #pragma unroll
        for (int mt = 0; mt < 4; ++mt) {
            float v0 = acc[mt][0]; v0 = v0 > 0.f ? v0 : a1v * v0;
            float v1 = acc[mt][1]; v1 = v1 > 0.f ? v1 : a1v * v1;
            float v2 = acc[mt][2]; v2 = v2 > 0.f ? v2 : a1v * v2;
            float v3 = acc[mt][3]; v3 = v3 > 0.f ? v3 : a1v * v3;
            *(uint2*)&myH1[ln16 * PW + mt * 16 + g * 4] =
                make_uint2(cvtpk(v0, v1), cvtpk(v2, v3));
        }

        // layer 2: D2[m][s] = W2T @ h1T, b2 as C-init
        f32x4 acc2[2] = { b2v[0], b2v[1] };
        #pragma unroll
        for (int w = 0; w < 2; ++w) {
            bf16x8 Bh = *(const bf16x8*)&myH1[ln16 * PW + w * 32 + g * 8];
            #pragma unroll
            for (int mt2 = 0; mt2 < 2; ++mt2) {
                bf16x8 ah = *(const bf16x8*)&sW2h[(mt2 * 16 + ln16) * PW + w * 32 + g * 8];
                acc2[mt2] = __builtin_amdgcn_mfma_f32_16x16x32_bf16(ah, Bh, acc2[mt2], 0, 0, 0);
            }
        }

        // layer 3: prelu + dot W3, reduce over lane-groups, score -> LDS
        float part = 0.f;
        #pragma unroll
        for (int mt2 = 0; mt2 < 2; ++mt2) {
            #pragma unroll
            for (int i = 0; i < 4; ++i) {
                float v = acc2[mt2][i];
                v = v > 0.f ? v : a2v * v;
                part += v * w3v[mt2][i];
            }
        }
        part += __shfl_xor(part, 16);
        part += __shfl_xor(part, 32);
        const int s = st * 16 + ln16;
        if (lane < 16 && s < 200) sSc[s] = part + b3v;
    };

    // ---- main loop: barrier-free, software-pipelined keys ----
    #pragma unroll
    for (int it = 0; it < 4; ++it) {
        const int st  = wave + 4 * it;       // wave-uniform
        const int stn = st + 4;
        K4 nxt = cur;
        if (stn < 13) nxt = loadKeys(stn);   // prefetch next tile
        if (st  < 13) computeTile(cur, st);
        cur = nxt;
    }
    __syncthreads();

    // ---- masked softmax over 200 scores (wave 3 holds prefetched mask) ----
    if (wave == 3) {
        float v[4];
        float M = -INFINITY;
        #pragma unroll
        for (int c = 0; c < 4; ++c) {
            int s = lane + 64 * c;
            v[c] = (s < S && mval[c]) ? sSc[s] : -INFINITY;
            M = fmaxf(M, v[c]);
        }
        #pragma unroll
        for (int off = 32; off > 0; off >>= 1) M = fmaxf(M, __shfl_xor(M, off));
        float Z = 0.f, e[4];
        #pragma unroll
        for (int c = 0; c < 4; ++c) { e[c] = mval[c] ? __expf(v[c] - M) : 0.f; Z += e[c]; }
        #pragma unroll
        for (int off = 32; off > 0; off >>= 1) Z += __shfl_xor(Z, off);
        const float inv = Z > 0.f ? 1.f / Z : 0.f;
        #pragma unroll
        for (int c = 0; c < 4; ++c) { int s = lane + 64 * c; if (s < S) sSc[s] = e[c] * inv; }
    }
    __syncthreads();

    // ---- weighted key sum (keys re-read, L2/L3-hot; weights from LDS) ----
    {
        const int d = lane;
        float acc = 0.f;
        #pragma unroll 5
        for (int i = 0; i < 50; ++i) {
            int s = wave * 50 + i;
            acc += sSc[s] * keys[((size_t)b * S + s) * D + d];
        }
        sQp[wave][d] = acc;
    }
    __syncthreads();
    if (t < 64)
        outh[((size_t)b * H + h) * D + t] = sQp[0][t] + sQp[1][t] + sQp[2][t] + sQp[3][t];
}

// ---------------------------------------------------------------------------
// Projection: out[b] = (mean_h outh[b,h,:]) @ Wo + bo.  4 b-rows per block.
// ---------------------------------------------------------------------------
__global__ __launch_bounds__(256) void proj_kernel(
    const float* __restrict__ outh, const float* __restrict__ Wo,
    const float* __restrict__ bo, float* __restrict__ out)
{
    __shared__ float comb[4][64];
    const int t = threadIdx.x, bb = t >> 6, j = t & 63;
    const size_t b = (size_t)blockIdx.x * 4 + bb;

    const float* oh = outh + b * H * D;
    comb[bb][j] = 0.25f * (oh[j] + oh[64 + j] + oh[128 + j] + oh[192 + j]);
    __syncthreads();

    float o = bo[j];
    #pragma unroll 8
    for (int d = 0; d < 64; ++d)
        o += comb[bb][d] * Wo[d * 64 + j];
    out[b * D + j] = o;
}

// ---------------------------------------------------------------------------
extern "C" void kernel_launch(void* const* d_in, const int* in_sizes, int n_in,
                              void* d_out, int out_size, void* d_ws, size_t ws_size,
                              hipStream_t stream) {
    const float* query = (const float*)d_in[0];
    const float* keys  = (const float*)d_in[1];
    const int*   mask  = (const int*)d_in[2];
    const float* W1 = (const float*)d_in[3];
    const float* b1 = (const float*)d_in[4];
    const float* a1 = (const float*)d_in[5];
    const float* W2 = (const float*)d_in[6];
    const float* b2 = (const float*)d_in[7];
    const float* a2 = (const float*)d_in[8];
    const float* W3 = (const float*)d_in[9];
    const float* b3 = (const float*)d_in[10];
    const float* Wo = (const float*)d_in[11];
    const float* bo = (const float*)d_in[12];

    float* out  = (float*)d_out;
    float* outh = (float*)d_ws;   // B*H*D floats = 2 MB

    score_attend_kernel<<<dim3(B * H), 256, 0, stream>>>(
        query, keys, mask, W1, b1, a1, W2, b2, a2, W3, b3, outh);
    proj_kernel<<<dim3(B / 4), 256, 0, stream>>>(outh, Wo, bo, out);
}